// Round 10
// baseline (397.790 us; speedup 1.0000x reference)
//
#include <hip/hip_runtime.h>

#define NTOK 256
#define DIM  128
#define NWIN 64

typedef __bf16 bf16x8 __attribute__((ext_vector_type(8)));
typedef __bf16 bf16x4 __attribute__((ext_vector_type(4)));
typedef float  f32x4  __attribute__((ext_vector_type(4)));

__device__ __forceinline__ float bf2f(unsigned short s) {
    union { unsigned u; float f; } x; x.u = ((unsigned)s) << 16; return x.f;
}
__device__ __forceinline__ unsigned f2bf_rne(float f) {
    union { float f; unsigned u; } x; x.f = f;
    return (x.u + 0x7FFF + ((x.u >> 16) & 1)) >> 16;
}
__device__ __forceinline__ int rel_idx(int i, int j) {
    int di = i >> 6, hi = (i >> 3) & 7, wi = i & 7;
    int dj = j >> 6, hj = (j >> 3) & 7, wj = j & 7;
    return 225 * (di - dj + 3) + 15 * (hi - hj + 7) + (wi - wj + 7);
}
__device__ __forceinline__ int swz64(int row, int b) { return row * 64  + (b ^ (((row >> 1) & 3) << 4)); }
__device__ __forceinline__ int swzV (int d,   int b) { return d   * 512 + (b ^ ((d & 7) << 4)); }

// ===================== ws layout =====================
#define BIAS_OFF 0u            // 4*256*256 bf16   = 512 KB
#define MASK_OFF 0x80000u      // 64*256*256 bf16  = 8 MB
#define WBF_OFF  0x880000u     // 384*128 bf16     = 96 KB
#define NEED3    0x898000u     // ~8.6 MB

__global__ void prep_kernel(const float* __restrict__ mask, const float* __restrict__ table,
                            const float* __restrict__ qkv_w,
                            unsigned short* __restrict__ bias, unsigned short* __restrict__ maskbf,
                            unsigned short* __restrict__ wbf) {
    int gid = blockIdx.x * 256 + threadIdx.x;
    if (gid < 262144) {
        int j = gid & 255, i = (gid >> 8) & 255, h = gid >> 16;
        bias[gid] = (unsigned short)f2bf_rne(table[rel_idx(i, j) * 4 + h]);
    } else if (gid < 262144 + 4194304) {
        int m = gid - 262144;
        maskbf[m] = (unsigned short)f2bf_rne(mask[m]);
    } else if (gid < 262144 + 4194304 + 49152) {
        int v = gid - 4456448;
        wbf[v] = (unsigned short)f2bf_rne(qkv_w[v]);
    }
}

// ---- fused proj + attention: one block per (bb,h); 56 KB LDS -> 2 blocks/CU ----
// NO s_setprio anywhere: r8/r9 isolated it as the spill trigger under (512,4).
#define Q_L 0
#define K_L 16384
#define V_L 32768
#define P_L 49152
#define LDS6 57344

__global__ __launch_bounds__(512, 4) void attn8_kernel(
    const float* __restrict__ x, const unsigned short* __restrict__ wbf,
    const float* __restrict__ q_bias, const float* __restrict__ v_bias,
    const unsigned short* __restrict__ bias, const unsigned short* __restrict__ maskbf,
    float* __restrict__ out) {
    __shared__ char smem[LDS6];
    const int tid = threadIdx.x;
    const int bb = blockIdx.x >> 2, h = blockIdx.x & 3;
    const int wq = bb & 63;
    const int w = tid >> 6, lane = tid & 63, lr = lane & 15, lg = lane >> 4;
    const float SCALE = 0.17677669529663687f;       // 1/sqrt(32)
    const float qb0 = q_bias[h * 32 + lr], qb1 = q_bias[h * 32 + 16 + lr];
    const float vb0 = v_bias[h * 32 + lr], vb1 = v_bias[h * 32 + 16 + lr];

    // ---- projection: wave owns tokens [w*32, w*32+32); x A-frags global->reg (transient) ----
    #pragma unroll
    for (int mi = 0; mi < 2; ++mi) {
        const int mt = w * 2 + mi;
        const float* xrow = x + ((size_t)bb * 256 + mt * 16 + lr) * DIM;
        bf16x8 xa[4];
        #pragma unroll
        for (int kk = 0; kk < 4; ++kk) {
            const float* xp2 = xrow + kk * 32 + lg * 8;
            float4 f0 = *(const float4*)(xp2);
            float4 f1 = *(const float4*)(xp2 + 4);
            union { bf16x8 v; __bf16 e[8]; } u8;
            u8.e[0] = (__bf16)f0.x; u8.e[1] = (__bf16)f0.y; u8.e[2] = (__bf16)f0.z; u8.e[3] = (__bf16)f0.w;
            u8.e[4] = (__bf16)f1.x; u8.e[5] = (__bf16)f1.y; u8.e[6] = (__bf16)f1.z; u8.e[7] = (__bf16)f1.w;
            xa[kk] = u8.v;
        }
        #pragma unroll
        for (int nt = 0; nt < 6; ++nt) {
            const int sec = nt >> 1;                // 0=Q 1=K 2=V
            const int wrow = sec * 128 + h * 32 + (nt & 1) * 16 + lr;
            f32x4 acc = {0.f, 0.f, 0.f, 0.f};
            #pragma unroll
            for (int kk = 0; kk < 4; ++kk) {
                bf16x8 wb = *(const bf16x8*)(wbf + wrow * DIM + kk * 32 + lg * 8);
                acc = __builtin_amdgcn_mfma_f32_16x16x32_bf16(xa[kk], wb, acc, 0, 0, 0);
            }
            const int d = (nt & 1) * 16 + lr;
            if (sec == 0) {
                float b = (nt & 1) ? qb1 : qb0;
                #pragma unroll
                for (int r = 0; r < 4; ++r) {
                    int row = mt * 16 + lg * 4 + r;
                    *(__bf16*)(smem + Q_L + swz64(row, d * 2)) = (__bf16)((acc[r] + b) * SCALE);
                }
            } else if (sec == 1) {
                #pragma unroll
                for (int r = 0; r < 4; ++r) {
                    int row = mt * 16 + lg * 4 + r;
                    *(__bf16*)(smem + K_L + swz64(row, d * 2)) = (__bf16)acc[r];
                }
            } else {
                float b = (nt & 1) ? vb1 : vb0;
                union { bf16x4 v; __bf16 e[4]; } u4;
                #pragma unroll
                for (int r = 0; r < 4; ++r) u4.e[r] = (__bf16)(acc[r] + b);
                int nb = mt * 16 + lg * 4;
                *(bf16x4*)(smem + V_L + swzV(d, nb * 2)) = u4.v;
            }
        }
    }
    __syncthreads();

    const unsigned short* brow_base = bias + ((size_t)h << 16);
    const unsigned short* mrow_base = maskbf + ((size_t)wq << 16);
    char* pbuf = smem + P_L + w * 1024;

    #pragma unroll 1
    for (int tt = 0; tt < 2; ++tt) {
        const int rg = w * 32 + tt * 16 + lr;
        bf16x8 qf = *(bf16x8*)(smem + Q_L + swz64(rg, lg * 16));

        // S^T = K * Q^T : lane holds S[q=lr][j = kt*16 + lg*4 + r]
        f32x4 st[16];
        #pragma unroll
        for (int kt = 0; kt < 16; ++kt) {
            bf16x8 kf = *(bf16x8*)(smem + K_L + swz64(kt * 16 + lr, lg * 16));
            f32x4 z = {0.f, 0.f, 0.f, 0.f};
            st[kt] = __builtin_amdgcn_mfma_f32_16x16x32_bf16(kf, qf, z, 0, 0, 0);
        }

        // + bias + mask (bf16, interleaved loads — spill-safe form), row max
        const unsigned short* brow = brow_base + rg * 256 + lg * 4;
        const unsigned short* mrow = mrow_base + rg * 256 + lg * 4;
        float mx = -3.0e38f;
        #pragma unroll
        for (int kt = 0; kt < 16; ++kt) {
            ushort4 b4 = *(const ushort4*)(brow + kt * 16);
            ushort4 m4 = *(const ushort4*)(mrow + kt * 16);
            st[kt][0] += bf2f(b4.x) + bf2f(m4.x);
            st[kt][1] += bf2f(b4.y) + bf2f(m4.y);
            st[kt][2] += bf2f(b4.z) + bf2f(m4.z);
            st[kt][3] += bf2f(b4.w) + bf2f(m4.w);
            mx = fmaxf(mx, fmaxf(fmaxf(st[kt][0], st[kt][1]), fmaxf(st[kt][2], st[kt][3])));
        }
        mx = fmaxf(mx, __shfl_xor(mx, 16));
        mx = fmaxf(mx, __shfl_xor(mx, 32));
        float sum = 0.f;
        #pragma unroll
        for (int kt = 0; kt < 16; ++kt) {
            #pragma unroll
            for (int cc = 0; cc < 4; ++cc) {
                float e = __expf(st[kt][cc] - mx);
                st[kt][cc] = e;
                sum += e;
            }
        }
        sum += __shfl_xor(sum, 16);
        sum += __shfl_xor(sum, 32);
        float inv = 1.0f / sum;

        // ---- PV via per-wave LDS P staging (proven path) ----
        f32x4 oacc[2];
        oacc[0] = (f32x4){0.f, 0.f, 0.f, 0.f};
        oacc[1] = (f32x4){0.f, 0.f, 0.f, 0.f};
        #pragma unroll
        for (int s = 0; s < 8; ++s) {
            #pragma unroll
            for (int half = 0; half < 2; ++half) {
                f32x4 p = st[2 * s + half];
                union { bf16x4 v; __bf16 e[4]; } u4;
                u4.e[0] = (__bf16)(p[0] * inv);
                u4.e[1] = (__bf16)(p[1] * inv);
                u4.e[2] = (__bf16)(p[2] * inv);
                u4.e[3] = (__bf16)(p[3] * inv);
                *(bf16x4*)(pbuf + swz64(lr, half * 32 + lg * 8)) = u4.v;
            }
            bf16x8 af = *(bf16x8*)(pbuf + swz64(lr, lg * 16));
            #pragma unroll
            for (int u2 = 0; u2 < 2; ++u2) {
                bf16x8 vf = *(bf16x8*)(smem + V_L + swzV(u2 * 16 + lr, s * 64 + lg * 16));
                oacc[u2] = __builtin_amdgcn_mfma_f32_16x16x32_bf16(af, vf, oacc[u2], 0, 0, 0);
            }
        }
        float* op = out + (((size_t)bb * 256 + w * 32 + tt * 16) * 128) + h * 32;
        #pragma unroll
        for (int u2 = 0; u2 < 2; ++u2)
            #pragma unroll
            for (int r = 0; r < 4; ++r)
                op[(lg * 4 + r) * 128 + u2 * 16 + lr] = oacc[u2][r];
    }
}

// ===================== fallback (tiny ws): proven r4 fused path =====================
#define X_OFF 0
#define W_OFF 65536
#define QF_OFF 90112
#define KF_OFF 106496
#define VF_OFF 122880
#define LDS_BYTES 139264

__device__ __forceinline__ int swz256(int row, int b) { return row * 256 + (b ^ ((row & 7) << 4)); }

__global__ void bias_kernel(const float* __restrict__ table, unsigned short* __restrict__ bias) {
    int gid = blockIdx.x * 256 + threadIdx.x;
    int j = gid & 255, i = (gid >> 8) & 255, h = gid >> 16;
    bias[gid] = (unsigned short)f2bf_rne(table[rel_idx(i, j) * 4 + h]);
}

template <int MODE>
__global__ __launch_bounds__(512, 2) void attn_kernel(
    const float* __restrict__ x, const float* __restrict__ qkv_w,
    const float* __restrict__ q_bias, const float* __restrict__ v_bias,
    const unsigned short* __restrict__ aux16, const float* __restrict__ mask,
    const float* __restrict__ table, float* __restrict__ out) {
    extern __shared__ char smem[];
    const int tid = threadIdx.x;
    const int bb = blockIdx.x >> 2, h = blockIdx.x & 3;
    const int w = tid >> 6, lane = tid & 63, lr = lane & 15, lg = lane >> 4;

    const float* xp = x + (size_t)bb * (NTOK * DIM);
    #pragma unroll
    for (int it = 0; it < 8; ++it) {
        int base = (it * 512 + tid) * 8;
        int row = base >> 7, col = base & 127;
        float4 f0 = *(const float4*)(xp + base);
        float4 f1 = *(const float4*)(xp + base + 4);
        union { bf16x8 v; __bf16 e[8]; } u8;
        u8.e[0] = (__bf16)f0.x; u8.e[1] = (__bf16)f0.y; u8.e[2] = (__bf16)f0.z; u8.e[3] = (__bf16)f0.w;
        u8.e[4] = (__bf16)f1.x; u8.e[5] = (__bf16)f1.y; u8.e[6] = (__bf16)f1.z; u8.e[7] = (__bf16)f1.w;
        *(bf16x8*)(smem + X_OFF + swz256(row, col * 2)) = u8.v;
    }
    #pragma unroll
    for (int it = 0; it < 3; ++it) {
        int base = (it * 512 + tid) * 8;
        int row = base >> 7, col = base & 127;
        int sec = row >> 5, r5 = row & 31;
        const float* wp = qkv_w + ((sec * 128 + h * 32 + r5) * DIM + col);
        float4 f0 = *(const float4*)(wp);
        float4 f1 = *(const float4*)(wp + 4);
        union { bf16x8 v; __bf16 e[8]; } u8;
        u8.e[0] = (__bf16)f0.x; u8.e[1] = (__bf16)f0.y; u8.e[2] = (__bf16)f0.z; u8.e[3] = (__bf16)f0.w;
        u8.e[4] = (__bf16)f1.x; u8.e[5] = (__bf16)f1.y; u8.e[6] = (__bf16)f1.z; u8.e[7] = (__bf16)f1.w;
        *(bf16x8*)(smem + W_OFF + swz256(row, col * 2)) = u8.v;
    }
    __syncthreads();

    const float SCALE = 0.17677669529663687f;
    #pragma unroll
    for (int mi = 0; mi < 2; ++mi) {
        int mt = w * 2 + mi;
        bf16x8 xa[4];
        #pragma unroll
        for (int kk = 0; kk < 4; ++kk)
            xa[kk] = *(bf16x8*)(smem + X_OFF + swz256(mt * 16 + lr, kk * 64 + lg * 16));
        #pragma unroll
        for (int nt = 0; nt < 6; ++nt) {
            f32x4 acc = {0.f, 0.f, 0.f, 0.f};
            #pragma unroll
            for (int kk = 0; kk < 4; ++kk) {
                bf16x8 wb = *(bf16x8*)(smem + W_OFF + swz256(nt * 16 + lr, kk * 64 + lg * 16));
                acc = __builtin_amdgcn_mfma_f32_16x16x32_bf16(xa[kk], wb, acc, 0, 0, 0);
            }
            int sec = nt >> 1;
            int d = (nt & 1) * 16 + lr;
            float bias = 0.f;
            if (sec == 0) bias = q_bias[h * 32 + d];
            if (sec == 2) bias = v_bias[h * 32 + d];
            #pragma unroll
            for (int r = 0; r < 4; ++r) {
                int row = mt * 16 + lg * 4 + r;
                float val = acc[r] + bias;
                if (sec == 0) {
                    val *= SCALE;
                    *(__bf16*)(smem + QF_OFF + swz64(row, d * 2)) = (__bf16)val;
                } else if (sec == 1) {
                    *(__bf16*)(smem + KF_OFF + swz64(row, d * 2)) = (__bf16)val;
                } else {
                    *(__bf16*)(smem + VF_OFF + swzV(d, row * 2)) = (__bf16)val;
                }
            }
        }
    }
    __syncthreads();

    bf16x8 qf[2];
    #pragma unroll
    for (int tt = 0; tt < 2; ++tt)
        qf[tt] = *(bf16x8*)(smem + QF_OFF + swz64(w * 32 + tt * 16 + lr, lg * 16));

    f32x4 st[2][16];
    #pragma unroll
    for (int kt = 0; kt < 16; ++kt) {
        bf16x8 kf = *(bf16x8*)(smem + KF_OFF + swz64(kt * 16 + lr, lg * 16));
        f32x4 z = {0.f, 0.f, 0.f, 0.f};
        st[0][kt] = __builtin_amdgcn_mfma_f32_16x16x32_bf16(kf, qf[0], z, 0, 0, 0);
        st[1][kt] = __builtin_amdgcn_mfma_f32_16x16x32_bf16(kf, qf[1], z, 0, 0, 0);
    }

    const int w_idx = bb & 63;
    float inv[2];
    #pragma unroll
    for (int tt = 0; tt < 2; ++tt) {
        int rg = w * 32 + tt * 16 + lr;
        float mx = -3.0e38f;
        #pragma unroll
        for (int kt = 0; kt < 16; ++kt) {
            if (MODE == 1) {
                const unsigned short* brow = aux16 + (((size_t)h) << 16) + rg * 256 + lg * 4;
                const float* mrow = mask + (((size_t)w_idx) << 16) + rg * 256 + lg * 4;
                ushort4 c4 = *(const ushort4*)(brow + kt * 16);
                float4 m4 = *(const float4*)(mrow + kt * 16);
                st[tt][kt][0] += bf2f(c4.x) + m4.x;
                st[tt][kt][1] += bf2f(c4.y) + m4.y;
                st[tt][kt][2] += bf2f(c4.z) + m4.z;
                st[tt][kt][3] += bf2f(c4.w) + m4.w;
            } else {
                const float* mrow = mask + (((size_t)w_idx) << 16) + rg * 256 + lg * 4;
                float4 m4 = *(const float4*)(mrow + kt * 16);
                #pragma unroll
                for (int cc = 0; cc < 4; ++cc) {
                    int j = kt * 16 + lg * 4 + cc;
                    float m = (cc == 0) ? m4.x : (cc == 1) ? m4.y : (cc == 2) ? m4.z : m4.w;
                    st[tt][kt][cc] += table[rel_idx(rg, j) * 4 + h] + m;
                }
            }
            mx = fmaxf(mx, fmaxf(fmaxf(st[tt][kt][0], st[tt][kt][1]),
                                 fmaxf(st[tt][kt][2], st[tt][kt][3])));
        }
        mx = fmaxf(mx, __shfl_xor(mx, 16));
        mx = fmaxf(mx, __shfl_xor(mx, 32));
        float sum = 0.f;
        #pragma unroll
        for (int kt = 0; kt < 16; ++kt) {
            #pragma unroll
            for (int cc = 0; cc < 4; ++cc) {
                float e = __expf(st[tt][kt][cc] - mx);
                st[tt][kt][cc] = e;
                sum += e;
            }
        }
        sum += __shfl_xor(sum, 16);
        sum += __shfl_xor(sum, 32);
        inv[tt] = 1.0f / sum;
    }

    char* pbuf = smem + X_OFF + w * 2048;
    f32x4 oacc[2][2];
    #pragma unroll
    for (int tt = 0; tt < 2; ++tt)
        #pragma unroll
        for (int u = 0; u < 2; ++u)
            oacc[tt][u] = (f32x4){0.f, 0.f, 0.f, 0.f};

    #pragma unroll
    for (int s = 0; s < 8; ++s) {
        #pragma unroll
        for (int tt = 0; tt < 2; ++tt) {
            #pragma unroll
            for (int half = 0; half < 2; ++half) {
                f32x4 pv = st[tt][2 * s + half];
                union { bf16x4 v; __bf16 e[4]; } u4;
                u4.e[0] = (__bf16)(pv[0] * inv[tt]);
                u4.e[1] = (__bf16)(pv[1] * inv[tt]);
                u4.e[2] = (__bf16)(pv[2] * inv[tt]);
                u4.e[3] = (__bf16)(pv[3] * inv[tt]);
                *(bf16x4*)(pbuf + swz64(tt * 16 + lr, half * 32 + lg * 8)) = u4.v;
            }
        }
        bf16x8 vf[2];
        #pragma unroll
        for (int u = 0; u < 2; ++u)
            vf[u] = *(bf16x8*)(smem + VF_OFF + swzV(u * 16 + lr, s * 64 + lg * 16));
        #pragma unroll
        for (int tt = 0; tt < 2; ++tt) {
            bf16x8 af = *(bf16x8*)(pbuf + swz64(tt * 16 + lr, lg * 16));
            #pragma unroll
            for (int u = 0; u < 2; ++u)
                oacc[tt][u] = __builtin_amdgcn_mfma_f32_16x16x32_bf16(af, vf[u], oacc[tt][u], 0, 0, 0);
        }
    }

    float* op = out + (((size_t)bb * 256 + w * 32) * 128) + h * 32;
    #pragma unroll
    for (int tt = 0; tt < 2; ++tt)
        #pragma unroll
        for (int u = 0; u < 2; ++u)
            #pragma unroll
            for (int r = 0; r < 4; ++r)
                op[(tt * 16 + lg * 4 + r) * 128 + u * 16 + lr] = oacc[tt][u][r];
}

extern "C" void kernel_launch(void* const* d_in, const int* in_sizes, int n_in,
                              void* d_out, int out_size, void* d_ws, size_t ws_size,
                              hipStream_t stream) {
    const float* x      = (const float*)d_in[0];
    const float* mask   = (const float*)d_in[1];
    const float* qkv_w  = (const float*)d_in[2];
    const float* q_bias = (const float*)d_in[3];
    const float* v_bias = (const float*)d_in[4];
    const float* table  = (const float*)d_in[5];
    float* out = (float*)d_out;
    (void)in_sizes; (void)n_in; (void)out_size;

    if (ws_size >= (size_t)NEED3) {
        char* ws = (char*)d_ws;
        unsigned short* bias   = (unsigned short*)(ws + BIAS_OFF);
        unsigned short* maskbf = (unsigned short*)(ws + MASK_OFF);
        unsigned short* wbf    = (unsigned short*)(ws + WBF_OFF);
        prep_kernel<<<17600, 256, 0, stream>>>(mask, table, qkv_w, bias, maskbf, wbf);
        attn8_kernel<<<2048, 512, 0, stream>>>(x, wbf, q_bias, v_bias, bias, maskbf, out);
        return;
    }

    const size_t NEED_BIAS = (size_t)4 * 256 * 256 * 2;         // 512 KB
    if (ws_size >= NEED_BIAS) {
        unsigned short* bias = (unsigned short*)d_ws;
        bias_kernel<<<1024, 256, 0, stream>>>(table, bias);
        hipFuncSetAttribute((const void*)attn_kernel<1>,
                            hipFuncAttributeMaxDynamicSharedMemorySize, LDS_BYTES);
        attn_kernel<1><<<2048, 512, LDS_BYTES, stream>>>(x, qkv_w, q_bias, v_bias,
                                                         bias, mask, table, out);
    } else {
        hipFuncSetAttribute((const void*)attn_kernel<2>,
                            hipFuncAttributeMaxDynamicSharedMemorySize, LDS_BYTES);
        attn_kernel<2><<<2048, 512, LDS_BYTES, stream>>>(x, qkv_w, q_bias, v_bias,
                                                         nullptr, mask, table, out);
    }
}

// Round 12
// 242.795 us; speedup vs baseline: 1.6384x; 1.6384x over previous
//
#include <hip/hip_runtime.h>

#define NTOK 256
#define DIM  128
#define NWIN 64

typedef __bf16 bf16x8 __attribute__((ext_vector_type(8)));
typedef __bf16 bf16x4 __attribute__((ext_vector_type(4)));
typedef float  f32x4  __attribute__((ext_vector_type(4)));

__device__ __forceinline__ float bf2f(unsigned short s) {
    union { unsigned u; float f; } x; x.u = ((unsigned)s) << 16; return x.f;
}
__device__ __forceinline__ unsigned f2bf_rne(float f) {
    union { float f; unsigned u; } x; x.f = f;
    return (x.u + 0x7FFF + ((x.u >> 16) & 1)) >> 16;
}
__device__ __forceinline__ int rel_idx(int i, int j) {
    int di = i >> 6, hi = (i >> 3) & 7, wi = i & 7;
    int dj = j >> 6, hj = (j >> 3) & 7, wj = j & 7;
    return 225 * (di - dj + 3) + 15 * (hi - hj + 7) + (wi - wj + 7);
}
__device__ __forceinline__ int swz64(int row, int b) { return row * 64  + (b ^ (((row >> 1) & 3) << 4)); }
__device__ __forceinline__ int swzV (int d,   int b) { return d   * 512 + (b ^ ((d & 7) << 4)); }

// ===================== ws layout =====================
#define BIAS_OFF 0u            // 4*256*256 bf16   = 512 KB
#define MASK_OFF 0x80000u      // 64*256*256 bf16  = 8 MB
#define WBF_OFF  0x880000u     // 384*128 bf16     = 96 KB
#define NEED3    0x898000u     // ~8.6 MB

__global__ void prep_kernel(const float* __restrict__ mask, const float* __restrict__ table,
                            const float* __restrict__ qkv_w,
                            unsigned short* __restrict__ bias, unsigned short* __restrict__ maskbf,
                            unsigned short* __restrict__ wbf) {
    int gid = blockIdx.x * 256 + threadIdx.x;
    if (gid < 262144) {
        int j = gid & 255, i = (gid >> 8) & 255, h = gid >> 16;
        bias[gid] = (unsigned short)f2bf_rne(table[rel_idx(i, j) * 4 + h]);
    } else if (gid < 262144 + 4194304) {
        int m = gid - 262144;
        maskbf[m] = (unsigned short)f2bf_rne(mask[m]);
    } else if (gid < 262144 + 4194304 + 49152) {
        int v = gid - 4456448;
        wbf[v] = (unsigned short)f2bf_rne(qkv_w[v]);
    }
}

// ---- fused proj + ONLINE-softmax attention: one block per (bb,h); 56 KB LDS ----
// st[16] spills under the (512,4) cap (r7-r10). Online 2-tile softmax uses st[8].
// BUGFIX vs r11: oacc rows are q = lg*4+r, so the per-tile rescale factor must be
// fetched from lane (lg*4+r) — same remap as the final invq — not applied as lane-lr's.
#define Q_L 0
#define K_L 16384
#define V_L 32768
#define P_L 49152
#define LDS6 57344

__global__ __launch_bounds__(512, 4) void attn9_kernel(
    const float* __restrict__ x, const unsigned short* __restrict__ wbf,
    const float* __restrict__ q_bias, const float* __restrict__ v_bias,
    const unsigned short* __restrict__ bias, const unsigned short* __restrict__ maskbf,
    float* __restrict__ out) {
    __shared__ char smem[LDS6];
    const int tid = threadIdx.x;
    const int bb = blockIdx.x >> 2, h = blockIdx.x & 3;
    const int wq = bb & 63;
    const int w = tid >> 6, lane = tid & 63, lr = lane & 15, lg = lane >> 4;
    const float SCALE = 0.17677669529663687f;       // 1/sqrt(32)
    const float qb0 = q_bias[h * 32 + lr], qb1 = q_bias[h * 32 + 16 + lr];
    const float vb0 = v_bias[h * 32 + lr], vb1 = v_bias[h * 32 + 16 + lr];

    // ---- projection: wave owns tokens [w*32, w*32+32); x A-frags global->reg (transient) ----
    #pragma unroll
    for (int mi = 0; mi < 2; ++mi) {
        const int mt = w * 2 + mi;
        const float* xrow = x + ((size_t)bb * 256 + mt * 16 + lr) * DIM;
        bf16x8 xa[4];
        #pragma unroll
        for (int kk = 0; kk < 4; ++kk) {
            const float* xp2 = xrow + kk * 32 + lg * 8;
            float4 f0 = *(const float4*)(xp2);
            float4 f1 = *(const float4*)(xp2 + 4);
            union { bf16x8 v; __bf16 e[8]; } u8;
            u8.e[0] = (__bf16)f0.x; u8.e[1] = (__bf16)f0.y; u8.e[2] = (__bf16)f0.z; u8.e[3] = (__bf16)f0.w;
            u8.e[4] = (__bf16)f1.x; u8.e[5] = (__bf16)f1.y; u8.e[6] = (__bf16)f1.z; u8.e[7] = (__bf16)f1.w;
            xa[kk] = u8.v;
        }
        #pragma unroll
        for (int nt = 0; nt < 6; ++nt) {
            const int sec = nt >> 1;                // 0=Q 1=K 2=V
            const int wrow = sec * 128 + h * 32 + (nt & 1) * 16 + lr;
            f32x4 acc = {0.f, 0.f, 0.f, 0.f};
            #pragma unroll
            for (int kk = 0; kk < 4; ++kk) {
                bf16x8 wb = *(const bf16x8*)(wbf + wrow * DIM + kk * 32 + lg * 8);
                acc = __builtin_amdgcn_mfma_f32_16x16x32_bf16(xa[kk], wb, acc, 0, 0, 0);
            }
            const int d = (nt & 1) * 16 + lr;
            if (sec == 0) {
                float b = (nt & 1) ? qb1 : qb0;
                #pragma unroll
                for (int r = 0; r < 4; ++r) {
                    int row = mt * 16 + lg * 4 + r;
                    *(__bf16*)(smem + Q_L + swz64(row, d * 2)) = (__bf16)((acc[r] + b) * SCALE);
                }
            } else if (sec == 1) {
                #pragma unroll
                for (int r = 0; r < 4; ++r) {
                    int row = mt * 16 + lg * 4 + r;
                    *(__bf16*)(smem + K_L + swz64(row, d * 2)) = (__bf16)acc[r];
                }
            } else {
                float b = (nt & 1) ? vb1 : vb0;
                union { bf16x4 v; __bf16 e[4]; } u4;
                #pragma unroll
                for (int r = 0; r < 4; ++r) u4.e[r] = (__bf16)(acc[r] + b);
                int nb = mt * 16 + lg * 4;
                *(bf16x4*)(smem + V_L + swzV(d, nb * 2)) = u4.v;
            }
        }
    }
    __syncthreads();

    const unsigned short* brow_base = bias + ((size_t)h << 16);
    const unsigned short* mrow_base = maskbf + ((size_t)wq << 16);
    char* pbuf = smem + P_L + w * 1024;

    #pragma unroll 1
    for (int tt = 0; tt < 2; ++tt) {
        const int rg = w * 32 + tt * 16 + lr;
        bf16x8 qf = *(bf16x8*)(smem + Q_L + swz64(rg, lg * 16));
        const unsigned short* brow = brow_base + rg * 256 + lg * 4;
        const unsigned short* mrow = mrow_base + rg * 256 + lg * 4;

        float m_run = -3.0e38f, l_run = 0.f;
        f32x4 oacc[2];
        oacc[0] = (f32x4){0.f, 0.f, 0.f, 0.f};
        oacc[1] = (f32x4){0.f, 0.f, 0.f, 0.f};

        #pragma unroll 1
        for (int kb = 0; kb < 2; ++kb) {
            // S^T tile = K * Q^T : lane holds S[q=lr][j = (kb*8+kt)*16 + lg*4 + r]
            f32x4 st[8];
            #pragma unroll
            for (int kt = 0; kt < 8; ++kt) {
                bf16x8 kf = *(bf16x8*)(smem + K_L + swz64((kb * 8 + kt) * 16 + lr, lg * 16));
                f32x4 z = {0.f, 0.f, 0.f, 0.f};
                st[kt] = __builtin_amdgcn_mfma_f32_16x16x32_bf16(kf, qf, z, 0, 0, 0);
            }
            // + bias + mask, tile max (per row q=lr)
            float pmax = -3.0e38f;
            #pragma unroll
            for (int kt = 0; kt < 8; ++kt) {
                ushort4 b4 = *(const ushort4*)(brow + (kb * 8 + kt) * 16);
                ushort4 m4 = *(const ushort4*)(mrow + (kb * 8 + kt) * 16);
                st[kt][0] += bf2f(b4.x) + bf2f(m4.x);
                st[kt][1] += bf2f(b4.y) + bf2f(m4.y);
                st[kt][2] += bf2f(b4.z) + bf2f(m4.z);
                st[kt][3] += bf2f(b4.w) + bf2f(m4.w);
                pmax = fmaxf(pmax, fmaxf(fmaxf(st[kt][0], st[kt][1]), fmaxf(st[kt][2], st[kt][3])));
            }
            pmax = fmaxf(pmax, __shfl_xor(pmax, 16));
            pmax = fmaxf(pmax, __shfl_xor(pmax, 32));
            // online rescale: l_run/st are per-row q=lr; oacc rows are q=lg*4+r -> shfl remap
            float m_new = fmaxf(m_run, pmax);
            float scale = __expf(m_run - m_new);
            m_run = m_new;
            l_run *= scale;
            #pragma unroll
            for (int r = 0; r < 4; ++r) {
                float sq = __shfl(scale, lg * 4 + r);
                oacc[0][r] *= sq;
                oacc[1][r] *= sq;
            }
            float sum = 0.f;
            #pragma unroll
            for (int kt = 0; kt < 8; ++kt) {
                #pragma unroll
                for (int cc = 0; cc < 4; ++cc) {
                    float e = __expf(st[kt][cc] - m_new);
                    st[kt][cc] = e;
                    sum += e;
                }
            }
            l_run += sum;

            // PV for this tile: unnormalized P (<=1) via per-wave LDS staging
            #pragma unroll
            for (int s = 0; s < 4; ++s) {
                #pragma unroll
                for (int half = 0; half < 2; ++half) {
                    f32x4 p = st[2 * s + half];
                    union { bf16x4 v; __bf16 e[4]; } u4;
                    u4.e[0] = (__bf16)p[0];
                    u4.e[1] = (__bf16)p[1];
                    u4.e[2] = (__bf16)p[2];
                    u4.e[3] = (__bf16)p[3];
                    *(bf16x4*)(pbuf + swz64(lr, half * 32 + lg * 8)) = u4.v;
                }
                bf16x8 af = *(bf16x8*)(pbuf + swz64(lr, lg * 16));
                const int sg = kb * 4 + s;
                #pragma unroll
                for (int u2 = 0; u2 < 2; ++u2) {
                    bf16x8 vf = *(bf16x8*)(smem + V_L + swzV(u2 * 16 + lr, sg * 64 + lg * 16));
                    oacc[u2] = __builtin_amdgcn_mfma_f32_16x16x32_bf16(af, vf, oacc[u2], 0, 0, 0);
                }
            }
        }
        // total row sum across the 4 lane-groups, then normalize per OUTPUT row (q = lg*4+r)
        l_run += __shfl_xor(l_run, 16);
        l_run += __shfl_xor(l_run, 32);
        float inv = 1.0f / l_run;
        float invq[4];
        #pragma unroll
        for (int r = 0; r < 4; ++r) invq[r] = __shfl(inv, lg * 4 + r);

        float* op = out + (((size_t)bb * 256 + w * 32 + tt * 16) * 128) + h * 32;
        #pragma unroll
        for (int u2 = 0; u2 < 2; ++u2)
            #pragma unroll
            for (int r = 0; r < 4; ++r)
                op[(lg * 4 + r) * 128 + u2 * 16 + lr] = oacc[u2][r] * invq[r];
    }
}

// ===================== fallback (tiny ws): proven r4 fused path =====================
#define X_OFF 0
#define W_OFF 65536
#define QF_OFF 90112
#define KF_OFF 106496
#define VF_OFF 122880
#define LDS_BYTES 139264

__device__ __forceinline__ int swz256(int row, int b) { return row * 256 + (b ^ ((row & 7) << 4)); }

__global__ void bias_kernel(const float* __restrict__ table, unsigned short* __restrict__ bias) {
    int gid = blockIdx.x * 256 + threadIdx.x;
    int j = gid & 255, i = (gid >> 8) & 255, h = gid >> 16;
    bias[gid] = (unsigned short)f2bf_rne(table[rel_idx(i, j) * 4 + h]);
}

template <int MODE>
__global__ __launch_bounds__(512, 2) void attn_kernel(
    const float* __restrict__ x, const float* __restrict__ qkv_w,
    const float* __restrict__ q_bias, const float* __restrict__ v_bias,
    const unsigned short* __restrict__ aux16, const float* __restrict__ mask,
    const float* __restrict__ table, float* __restrict__ out) {
    extern __shared__ char smem[];
    const int tid = threadIdx.x;
    const int bb = blockIdx.x >> 2, h = blockIdx.x & 3;
    const int w = tid >> 6, lane = tid & 63, lr = lane & 15, lg = lane >> 4;

    const float* xp = x + (size_t)bb * (NTOK * DIM);
    #pragma unroll
    for (int it = 0; it < 8; ++it) {
        int base = (it * 512 + tid) * 8;
        int row = base >> 7, col = base & 127;
        float4 f0 = *(const float4*)(xp + base);
        float4 f1 = *(const float4*)(xp + base + 4);
        union { bf16x8 v; __bf16 e[8]; } u8;
        u8.e[0] = (__bf16)f0.x; u8.e[1] = (__bf16)f0.y; u8.e[2] = (__bf16)f0.z; u8.e[3] = (__bf16)f0.w;
        u8.e[4] = (__bf16)f1.x; u8.e[5] = (__bf16)f1.y; u8.e[6] = (__bf16)f1.z; u8.e[7] = (__bf16)f1.w;
        *(bf16x8*)(smem + X_OFF + swz256(row, col * 2)) = u8.v;
    }
    #pragma unroll
    for (int it = 0; it < 3; ++it) {
        int base = (it * 512 + tid) * 8;
        int row = base >> 7, col = base & 127;
        int sec = row >> 5, r5 = row & 31;
        const float* wp = qkv_w + ((sec * 128 + h * 32 + r5) * DIM + col);
        float4 f0 = *(const float4*)(wp);
        float4 f1 = *(const float4*)(wp + 4);
        union { bf16x8 v; __bf16 e[8]; } u8;
        u8.e[0] = (__bf16)f0.x; u8.e[1] = (__bf16)f0.y; u8.e[2] = (__bf16)f0.z; u8.e[3] = (__bf16)f0.w;
        u8.e[4] = (__bf16)f1.x; u8.e[5] = (__bf16)f1.y; u8.e[6] = (__bf16)f1.z; u8.e[7] = (__bf16)f1.w;
        *(bf16x8*)(smem + W_OFF + swz256(row, col * 2)) = u8.v;
    }
    __syncthreads();

    const float SCALE = 0.17677669529663687f;
    #pragma unroll
    for (int mi = 0; mi < 2; ++mi) {
        int mt = w * 2 + mi;
        bf16x8 xa[4];
        #pragma unroll
        for (int kk = 0; kk < 4; ++kk)
            xa[kk] = *(bf16x8*)(smem + X_OFF + swz256(mt * 16 + lr, kk * 64 + lg * 16));
        #pragma unroll
        for (int nt = 0; nt < 6; ++nt) {
            f32x4 acc = {0.f, 0.f, 0.f, 0.f};
            #pragma unroll
            for (int kk = 0; kk < 4; ++kk) {
                bf16x8 wb = *(bf16x8*)(smem + W_OFF + swz256(nt * 16 + lr, kk * 64 + lg * 16));
                acc = __builtin_amdgcn_mfma_f32_16x16x32_bf16(xa[kk], wb, acc, 0, 0, 0);
            }
            int sec = nt >> 1;
            int d = (nt & 1) * 16 + lr;
            float bias = 0.f;
            if (sec == 0) bias = q_bias[h * 32 + d];
            if (sec == 2) bias = v_bias[h * 32 + d];
            #pragma unroll
            for (int r = 0; r < 4; ++r) {
                int row = mt * 16 + lg * 4 + r;
                float val = acc[r] + bias;
                if (sec == 0) {
                    val *= SCALE;
                    *(__bf16*)(smem + QF_OFF + swz64(row, d * 2)) = (__bf16)val;
                } else if (sec == 1) {
                    *(__bf16*)(smem + KF_OFF + swz64(row, d * 2)) = (__bf16)val;
                } else {
                    *(__bf16*)(smem + VF_OFF + swzV(d, row * 2)) = (__bf16)val;
                }
            }
        }
    }
    __syncthreads();

    bf16x8 qf[2];
    #pragma unroll
    for (int tt = 0; tt < 2; ++tt)
        qf[tt] = *(bf16x8*)(smem + QF_OFF + swz64(w * 32 + tt * 16 + lr, lg * 16));

    f32x4 st[2][16];
    #pragma unroll
    for (int kt = 0; kt < 16; ++kt) {
        bf16x8 kf = *(bf16x8*)(smem + KF_OFF + swz64(kt * 16 + lr, lg * 16));
        f32x4 z = {0.f, 0.f, 0.f, 0.f};
        st[0][kt] = __builtin_amdgcn_mfma_f32_16x16x32_bf16(kf, qf[0], z, 0, 0, 0);
        st[1][kt] = __builtin_amdgcn_mfma_f32_16x16x32_bf16(kf, qf[1], z, 0, 0, 0);
    }

    const int w_idx = bb & 63;
    float inv[2];
    #pragma unroll
    for (int tt = 0; tt < 2; ++tt) {
        int rg = w * 32 + tt * 16 + lr;
        float mx = -3.0e38f;
        #pragma unroll
        for (int kt = 0; kt < 16; ++kt) {
            if (MODE == 1) {
                const unsigned short* brow = aux16 + (((size_t)h) << 16) + rg * 256 + lg * 4;
                const float* mrow = mask + (((size_t)w_idx) << 16) + rg * 256 + lg * 4;
                ushort4 c4 = *(const ushort4*)(brow + kt * 16);
                float4 m4 = *(const float4*)(mrow + kt * 16);
                st[tt][kt][0] += bf2f(c4.x) + m4.x;
                st[tt][kt][1] += bf2f(c4.y) + m4.y;
                st[tt][kt][2] += bf2f(c4.z) + m4.z;
                st[tt][kt][3] += bf2f(c4.w) + m4.w;
            } else {
                const float* mrow = mask + (((size_t)w_idx) << 16) + rg * 256 + lg * 4;
                float4 m4 = *(const float4*)(mrow + kt * 16);
                #pragma unroll
                for (int cc = 0; cc < 4; ++cc) {
                    int j = kt * 16 + lg * 4 + cc;
                    float m = (cc == 0) ? m4.x : (cc == 1) ? m4.y : (cc == 2) ? m4.z : m4.w;
                    st[tt][kt][cc] += table[rel_idx(rg, j) * 4 + h] + m;
                }
            }
            mx = fmaxf(mx, fmaxf(fmaxf(st[tt][kt][0], st[tt][kt][1]),
                                 fmaxf(st[tt][kt][2], st[tt][kt][3])));
        }
        mx = fmaxf(mx, __shfl_xor(mx, 16));
        mx = fmaxf(mx, __shfl_xor(mx, 32));
        float sum = 0.f;
        #pragma unroll
        for (int kt = 0; kt < 16; ++kt) {
            #pragma unroll
            for (int cc = 0; cc < 4; ++cc) {
                float e = __expf(st[tt][kt][cc] - mx);
                st[tt][kt][cc] = e;
                sum += e;
            }
        }
        sum += __shfl_xor(sum, 16);
        sum += __shfl_xor(sum, 32);
        inv[tt] = 1.0f / sum;
    }

    char* pbuf = smem + X_OFF + w * 2048;
    f32x4 oacc[2][2];
    #pragma unroll
    for (int tt = 0; tt < 2; ++tt)
        #pragma unroll
        for (int u = 0; u < 2; ++u)
            oacc[tt][u] = (f32x4){0.f, 0.f, 0.f, 0.f};

    #pragma unroll
    for (int s = 0; s < 8; ++s) {
        #pragma unroll
        for (int tt = 0; tt < 2; ++tt) {
            #pragma unroll
            for (int half = 0; half < 2; ++half) {
                f32x4 pv = st[tt][2 * s + half];
                union { bf16x4 v; __bf16 e[4]; } u4;
                u4.e[0] = (__bf16)(pv[0] * inv[tt]);
                u4.e[1] = (__bf16)(pv[1] * inv[tt]);
                u4.e[2] = (__bf16)(pv[2] * inv[tt]);
                u4.e[3] = (__bf16)(pv[3] * inv[tt]);
                *(bf16x4*)(pbuf + swz64(tt * 16 + lr, half * 32 + lg * 8)) = u4.v;
            }
        }
        bf16x8 vf[2];
        #pragma unroll
        for (int u = 0; u < 2; ++u)
            vf[u] = *(bf16x8*)(smem + VF_OFF + swzV(u * 16 + lr, s * 64 + lg * 16));
        #pragma unroll
        for (int tt = 0; tt < 2; ++tt) {
            bf16x8 af = *(bf16x8*)(pbuf + swz64(tt * 16 + lr, lg * 16));
            #pragma unroll
            for (int u = 0; u < 2; ++u)
                oacc[tt][u] = __builtin_amdgcn_mfma_f32_16x16x32_bf16(af, vf[u], oacc[tt][u], 0, 0, 0);
        }
    }

    float* op = out + (((size_t)bb * 256 + w * 32) * 128) + h * 32;
    #pragma unroll
    for (int tt = 0; tt < 2; ++tt)
        #pragma unroll
        for (int u = 0; u < 2; ++u)
            #pragma unroll
            for (int r = 0; r < 4; ++r)
                op[(tt * 16 + lg * 4 + r) * 128 + u * 16 + lr] = oacc[tt][u][r];
}

extern "C" void kernel_launch(void* const* d_in, const int* in_sizes, int n_in,
                              void* d_out, int out_size, void* d_ws, size_t ws_size,
                              hipStream_t stream) {
    const float* x      = (const float*)d_in[0];
    const float* mask   = (const float*)d_in[1];
    const float* qkv_w  = (const float*)d_in[2];
    const float* q_bias = (const float*)d_in[3];
    const float* v_bias = (const float*)d_in[4];
    const float* table  = (const float*)d_in[5];
    float* out = (float*)d_out;
    (void)in_sizes; (void)n_in; (void)out_size;

    if (ws_size >= (size_t)NEED3) {
        char* ws = (char*)d_ws;
        unsigned short* bias   = (unsigned short*)(ws + BIAS_OFF);
        unsigned short* maskbf = (unsigned short*)(ws + MASK_OFF);
        unsigned short* wbf    = (unsigned short*)(ws + WBF_OFF);
        prep_kernel<<<17600, 256, 0, stream>>>(mask, table, qkv_w, bias, maskbf, wbf);
        attn9_kernel<<<2048, 512, 0, stream>>>(x, wbf, q_bias, v_bias, bias, maskbf, out);
        return;
    }

    const size_t NEED_BIAS = (size_t)4 * 256 * 256 * 2;         // 512 KB
    if (ws_size >= NEED_BIAS) {
        unsigned short* bias = (unsigned short*)d_ws;
        bias_kernel<<<1024, 256, 0, stream>>>(table, bias);
        hipFuncSetAttribute((const void*)attn_kernel<1>,
                            hipFuncAttributeMaxDynamicSharedMemorySize, LDS_BYTES);
        attn_kernel<1><<<2048, 512, LDS_BYTES, stream>>>(x, qkv_w, q_bias, v_bias,
                                                         bias, mask, table, out);
    } else {
        hipFuncSetAttribute((const void*)attn_kernel<2>,
                            hipFuncAttributeMaxDynamicSharedMemorySize, LDS_BYTES);
        attn_kernel<2><<<2048, 512, LDS_BYTES, stream>>>(x, qkv_w, q_bias, v_bias,
                                                         nullptr, mask, table, out);
    }
}